// Round 1
// baseline (1049.125 us; speedup 1.0000x reference)
//
#include <hip/hip_runtime.h>

// ---------------------------------------------------------------------------
// MultiHeadAttention: B=2, S=2048, D=1024, H=16, DEPTH=64
// out  = (2, 2047, 1024) fp32   att = (2, 16, 2047, 2047) fp32
// Strategy: bf16x3 split MFMA for Q/K path (accuracy), plain bf16 for V/O.
// ---------------------------------------------------------------------------

typedef __attribute__((ext_vector_type(8))) short bf16x8;
typedef __attribute__((ext_vector_type(4))) float f32x4;

#define MFMA_BF16(A, B, C) __builtin_amdgcn_mfma_f32_16x16x32_bf16(A, B, C, 0, 0, 0)

__device__ __forceinline__ short f2bf(float x) {
    unsigned u = __float_as_uint(x);
    u = u + 0x7FFFu + ((u >> 16) & 1u);   // RNE
    return (short)(u >> 16);
}
__device__ __forceinline__ float bf2f(short s) {
    return __uint_as_float(((unsigned)(unsigned short)s) << 16);
}
__device__ __forceinline__ int imin(int a, int b) { return a < b ? a : b; }

// ---------------------------------------------------------------------------
// Transpose 1024x1024 W -> T[n][k] = W[k][n], split into bf16 hi (+ optional lo)
// ---------------------------------------------------------------------------
__global__ __launch_bounds__(256) void transpose_split_kernel(
    const float* __restrict__ W, short* __restrict__ Thi, short* __restrict__ Tlo) {
    __shared__ float tile[32][33];
    const int tx = threadIdx.x & 31, ty = threadIdx.x >> 5;
    const int k0 = blockIdx.x * 32, n0 = blockIdx.y * 32;
#pragma unroll
    for (int p = 0; p < 4; ++p)
        tile[ty + p * 8][tx] = W[(size_t)(k0 + ty + p * 8) * 1024 + n0 + tx];
    __syncthreads();
#pragma unroll
    for (int p = 0; p < 4; ++p) {
        int n = n0 + ty + p * 8, k = k0 + tx;
        float x = tile[tx][ty + p * 8];
        short h = f2bf(x);
        Thi[(size_t)n * 1024 + k] = h;
        if (Tlo) Tlo[(size_t)n * 1024 + k] = f2bf(x - bf2f(h));
    }
}

// ---------------------------------------------------------------------------
// GEMM: C[M x 1024] = A[M x 1024] @ B[1024 x 1024] + bias
//   A: fp32 row-major (converted to bf16 hi/lo during LDS staging)
//   B: pre-transposed bf16 Bt[n][k] (hi, and lo if SPLIT)
//   SPLIT=1: 3-product bf16x3 (near-fp32). OUTMODE: 0=fp32, 1=bf16, 2=bf16 hi/lo
//   Block: 256 threads, 64x64 tile, K-step 32. Wave w: rows w*16..w*16+15.
// ---------------------------------------------------------------------------
template <int SPLIT, int OUTMODE>
__global__ __launch_bounds__(256) void gemm_kernel(
    const float* __restrict__ A, int M,
    const short* __restrict__ Bthi, const short* __restrict__ Btlo,
    const float* __restrict__ bias,
    float* __restrict__ Cf, short* __restrict__ Chi, short* __restrict__ Clo) {
    __shared__ __align__(16) short Ash[64 * 40];
    __shared__ __align__(16) short Asl[64 * 40];
    __shared__ __align__(16) short Bsh[64 * 40];
    __shared__ __align__(16) short Bsl[64 * 40];

    const int tid = threadIdx.x;
    const int wave = tid >> 6, lane = tid & 63;
    const int quad = lane >> 4, l16 = lane & 15;
    const int m0 = blockIdx.y * 64, n0 = blockIdx.x * 64;

    const int row_s = tid >> 2;          // 0..63 staging row
    const int k_s = (tid & 3) * 8;       // 0,8,16,24

    f32x4 acc[4];
#pragma unroll
    for (int s = 0; s < 4; ++s) acc[s] = (f32x4){0.f, 0.f, 0.f, 0.f};

    for (int k0 = 0; k0 < 1024; k0 += 32) {
        __syncthreads();
        {
            int arow = imin(m0 + row_s, M - 1);
            const float* ap = A + (size_t)arow * 1024 + k0 + k_s;
            float4 x0 = *(const float4*)ap;
            float4 x1 = *(const float4*)(ap + 4);
            float xs[8] = {x0.x, x0.y, x0.z, x0.w, x1.x, x1.y, x1.z, x1.w};
            bf16x8 hv, lv;
#pragma unroll
            for (int i2 = 0; i2 < 8; ++i2) {
                short h = f2bf(xs[i2]);
                hv[i2] = h;
                if (SPLIT) lv[i2] = f2bf(xs[i2] - bf2f(h));
            }
            *(bf16x8*)&Ash[row_s * 40 + k_s] = hv;
            if (SPLIT) *(bf16x8*)&Asl[row_s * 40 + k_s] = lv;

            const short* bp = Bthi + (size_t)(n0 + row_s) * 1024 + k0 + k_s;
            *(bf16x8*)&Bsh[row_s * 40 + k_s] = *(const bf16x8*)bp;
            if (SPLIT) {
                const short* bp2 = Btlo + (size_t)(n0 + row_s) * 1024 + k0 + k_s;
                *(bf16x8*)&Bsl[row_s * 40 + k_s] = *(const bf16x8*)bp2;
            }
        }
        __syncthreads();

        bf16x8 ah = *(const bf16x8*)&Ash[(wave * 16 + l16) * 40 + quad * 8];
        bf16x8 al;
        if (SPLIT) al = *(const bf16x8*)&Asl[(wave * 16 + l16) * 40 + quad * 8];
#pragma unroll
        for (int s = 0; s < 4; ++s) {
            bf16x8 bh = *(const bf16x8*)&Bsh[(s * 16 + l16) * 40 + quad * 8];
            acc[s] = MFMA_BF16(ah, bh, acc[s]);
            if (SPLIT) {
                bf16x8 bl = *(const bf16x8*)&Bsl[(s * 16 + l16) * 40 + quad * 8];
                acc[s] = MFMA_BF16(ah, bl, acc[s]);
                acc[s] = MFMA_BF16(al, bh, acc[s]);
            }
        }
    }

    // epilogue: C row = m0 + wave*16 + quad*4 + r, col = n0 + s*16 + l16
#pragma unroll
    for (int s = 0; s < 4; ++s) {
        int col = n0 + s * 16 + l16;
        float bv = bias[col];
#pragma unroll
        for (int r = 0; r < 4; ++r) {
            int row = m0 + wave * 16 + quad * 4 + r;
            if (row < M) {
                float c = acc[s][r] + bv;
                size_t off = (size_t)row * 1024 + col;
                if (OUTMODE == 0) {
                    Cf[off] = c;
                } else if (OUTMODE == 1) {
                    Chi[off] = f2bf(c);
                } else {
                    short h = f2bf(c);
                    Chi[off] = h;
                    Clo[off] = f2bf(c - bf2f(h));
                }
            }
        }
    }
}

// ---------------------------------------------------------------------------
// Fused causal attention.
//   Sliced semantics: att[b,h,i,j] = softmax_j<=i( QQ[b,i+1,h]·KK[b,j,h]/8 )
//   ctx[b,i,h*64+d]  = sum_j att * VV[b,j,h*64+d]
// Block: 64 q-rows (4 waves x 16). Two passes over 32-key tiles.
// No max-subtraction (|logit| bounded ~ +-5 by construction; exp safe in fp32).
// ---------------------------------------------------------------------------
__global__ __launch_bounds__(256) void attn_kernel(
    const short* __restrict__ QQh, const short* __restrict__ QQl,
    const short* __restrict__ KKh, const short* __restrict__ KKl,
    const short* __restrict__ VV,
    float* __restrict__ att, float* __restrict__ ctx) {
    __shared__ __align__(16) short Ksh[32 * 72];   // [key][depth] pitch 72
    __shared__ __align__(16) short Ksl[32 * 72];
    __shared__ __align__(16) short Vts[64 * 40];   // [depth][key] pitch 40
    __shared__ __align__(16) short Ps[4][16 * 40]; // per-wave P tile

    const int tid = threadIdx.x;
    const int wave = tid >> 6, lane = tid & 63;
    const int quad = lane >> 4, l16 = lane & 15;
    const int bx = blockIdx.x;
    const int qt = 31 - (bx & 31);          // big blocks dispatched first
    const int bh = bx >> 5;
    const int h = bh & 15, b = bh >> 4;
    const int i0 = qt * 64;

    // Q fragments (A operand): row m = l16 -> i = i0 + wave*16 + l16, q-row = i+1
    const int i_frag = i0 + wave * 16 + l16;
    const int qrow = imin(i_frag + 1, 2047);
    const size_t qoff = ((size_t)(b * 2048 + qrow)) * 1024 + h * 64;
    const bf16x8 qh0 = *(const bf16x8*)&QQh[qoff + 0 + quad * 8];
    const bf16x8 qh1 = *(const bf16x8*)&QQh[qoff + 32 + quad * 8];
    const bf16x8 ql0 = *(const bf16x8*)&QQl[qoff + 0 + quad * 8];
    const bf16x8 ql1 = *(const bf16x8*)&QQl[qoff + 32 + quad * 8];

    const int i_max = imin(i0 + 63, 2046);
    const int jt_max = i_max >> 5;
    const int wave_imax = imin(i0 + wave * 16 + 15, 2046);
    const int my_rowbase = i0 + wave * 16 + quad * 4;

    // staging decompositions
    const int kst_key = tid >> 3;            // 0..31
    const int kst_dd = (tid & 7) * 8;        // 0..56
    const int vst_key = tid & 31, vst_d0 = (tid >> 5) * 8;

    float lsum[4] = {0.f, 0.f, 0.f, 0.f};

    // ---------------- PASS A: softmax denominators ----------------
    for (int jt = 0; jt <= jt_max; ++jt) {
        __syncthreads();
        {
            int jg = imin(jt * 32 + kst_key, 2047);
            const size_t koff = ((size_t)(b * 2048 + jg)) * 1024 + h * 64 + kst_dd;
            *(bf16x8*)&Ksh[kst_key * 72 + kst_dd] = *(const bf16x8*)&KKh[koff];
            *(bf16x8*)&Ksl[kst_key * 72 + kst_dd] = *(const bf16x8*)&KKl[koff];
        }
        __syncthreads();
        if (jt * 32 <= wave_imax) {
#pragma unroll
            for (int s = 0; s < 2; ++s) {
                f32x4 sc = (f32x4){0.f, 0.f, 0.f, 0.f};
#pragma unroll
                for (int c = 0; c < 2; ++c) {
                    bf16x8 bh = *(const bf16x8*)&Ksh[(s * 16 + l16) * 72 + c * 32 + quad * 8];
                    bf16x8 bl = *(const bf16x8*)&Ksl[(s * 16 + l16) * 72 + c * 32 + quad * 8];
                    bf16x8 ah = (c == 0) ? qh0 : qh1;
                    bf16x8 al = (c == 0) ? ql0 : ql1;
                    sc = MFMA_BF16(ah, bh, sc);
                    sc = MFMA_BF16(ah, bl, sc);
                    sc = MFMA_BF16(al, bh, sc);
                }
                int j = jt * 32 + s * 16 + l16;
#pragma unroll
                for (int r = 0; r < 4; ++r) {
                    int i = my_rowbase + r;
                    if (j <= i && i <= 2046) lsum[r] += __expf(sc[r] * 0.125f);
                }
            }
        }
    }
#pragma unroll
    for (int m = 1; m < 16; m <<= 1) {
#pragma unroll
        for (int r = 0; r < 4; ++r) lsum[r] += __shfl_xor(lsum[r], m, 64);
    }
    float linv[4];
#pragma unroll
    for (int r = 0; r < 4; ++r) linv[r] = 1.0f / lsum[r];

    f32x4 cacc[4];
#pragma unroll
    for (int t = 0; t < 4; ++t) cacc[t] = (f32x4){0.f, 0.f, 0.f, 0.f};

    // ---------------- PASS B: att writes + ctx ----------------
    for (int jt = 0; jt <= jt_max; ++jt) {
        __syncthreads();
        {
            int jg = imin(jt * 32 + kst_key, 2047);
            const size_t koff = ((size_t)(b * 2048 + jg)) * 1024 + h * 64 + kst_dd;
            *(bf16x8*)&Ksh[kst_key * 72 + kst_dd] = *(const bf16x8*)&KKh[koff];
            *(bf16x8*)&Ksl[kst_key * 72 + kst_dd] = *(const bf16x8*)&KKl[koff];
            int vjg = imin(jt * 32 + vst_key, 2046);
            const size_t voff = ((size_t)(b * 2047 + vjg)) * 1024 + h * 64 + vst_d0;
            bf16x8 vv = *(const bf16x8*)&VV[voff];
#pragma unroll
            for (int q2 = 0; q2 < 8; ++q2) Vts[(vst_d0 + q2) * 40 + vst_key] = vv[q2];
        }
        __syncthreads();
        if (jt * 32 <= wave_imax) {
#pragma unroll
            for (int s = 0; s < 2; ++s) {
                f32x4 sc = (f32x4){0.f, 0.f, 0.f, 0.f};
#pragma unroll
                for (int c = 0; c < 2; ++c) {
                    bf16x8 bh = *(const bf16x8*)&Ksh[(s * 16 + l16) * 72 + c * 32 + quad * 8];
                    bf16x8 bl = *(const bf16x8*)&Ksl[(s * 16 + l16) * 72 + c * 32 + quad * 8];
                    bf16x8 ah = (c == 0) ? qh0 : qh1;
                    bf16x8 al = (c == 0) ? ql0 : ql1;
                    sc = MFMA_BF16(ah, bh, sc);
                    sc = MFMA_BF16(ah, bl, sc);
                    sc = MFMA_BF16(al, bh, sc);
                }
                int j = jt * 32 + s * 16 + l16;
#pragma unroll
                for (int r = 0; r < 4; ++r) {
                    int i = my_rowbase + r;
                    bool valid = (j <= i) && (i <= 2046);
                    float p = valid ? __expf(sc[r] * 0.125f) * linv[r] : 0.0f;
                    if (i <= 2046 && j <= 2046)
                        att[(((size_t)(b * 16 + h)) * 2047 + i) * 2047 + j] = p;
                    Ps[wave][(quad * 4 + r) * 40 + s * 16 + l16] = f2bf(p);
                }
            }
            // P (A-layout) x V^T (B-layout) -> ctx
            bf16x8 pa = *(const bf16x8*)&Ps[wave][l16 * 40 + quad * 8];
#pragma unroll
            for (int t = 0; t < 4; ++t) {
                bf16x8 vb = *(const bf16x8*)&Vts[(t * 16 + l16) * 40 + quad * 8];
                cacc[t] = MFMA_BF16(pa, vb, cacc[t]);
            }
        } else {
            // fully-masked tile for this wave: just write the zeros
#pragma unroll
            for (int s = 0; s < 2; ++s) {
                int j = jt * 32 + s * 16 + l16;
#pragma unroll
                for (int r = 0; r < 4; ++r) {
                    int i = my_rowbase + r;
                    if (i <= 2046 && j <= 2046)
                        att[(((size_t)(b * 16 + h)) * 2047 + i) * 2047 + j] = 0.0f;
                }
            }
        }
    }

    // ctx write (fp32 scratch)
#pragma unroll
    for (int t = 0; t < 4; ++t) {
#pragma unroll
        for (int r = 0; r < 4; ++r) {
            int i = my_rowbase + r;
            if (i <= 2046)
                ctx[((size_t)(b * 2047 + i)) * 1024 + h * 64 + t * 16 + l16] = cacc[t][r];
        }
    }

    // zero tail: att cols beyond the block's causal tiles
    const int js = (jt_max + 1) * 32;
    for (int rr = 0; rr < 64; ++rr) {
        int i = i0 + rr;
        if (i > 2046) break;
        float* rowp = att + (((size_t)(b * 16 + h)) * 2047 + i) * 2047;
        for (int cc = js + tid; cc < 2047; cc += 256) rowp[cc] = 0.0f;
    }
}

// ---------------------------------------------------------------------------
extern "C" void kernel_launch(void* const* d_in, const int* in_sizes, int n_in,
                              void* d_out, int out_size, void* d_ws, size_t ws_size,
                              hipStream_t stream) {
    (void)in_sizes; (void)n_in; (void)out_size; (void)ws_size;
    const float* q  = (const float*)d_in[0];
    const float* k  = (const float*)d_in[1];
    const float* v  = (const float*)d_in[2];
    // d_in[3] = mask (causality implemented directly)
    const float* Wq = (const float*)d_in[4];
    const float* bq = (const float*)d_in[5];
    const float* Wk = (const float*)d_in[6];
    const float* bk = (const float*)d_in[7];
    const float* Wv = (const float*)d_in[8];
    const float* bv = (const float*)d_in[9];
    const float* Wo = (const float*)d_in[10];
    const float* bo = (const float*)d_in[11];

    float* out = (float*)d_out;                     // 2*2047*1024
    float* att = out + (size_t)2 * 2047 * 1024;     // 2*16*2047*2047

    char* ws = (char*)d_ws;
    size_t off = 0;
    auto alloc = [&](size_t bytes) -> void* {
        void* p = ws + off;
        off += (bytes + 255) & ~(size_t)255;
        return p;
    };
    short* Wqt_h = (short*)alloc((size_t)1024 * 1024 * 2);
    short* Wqt_l = (short*)alloc((size_t)1024 * 1024 * 2);
    short* Wkt_h = (short*)alloc((size_t)1024 * 1024 * 2);
    short* Wkt_l = (short*)alloc((size_t)1024 * 1024 * 2);
    short* Wvt_h = (short*)alloc((size_t)1024 * 1024 * 2);
    short* Wot_h = (short*)alloc((size_t)1024 * 1024 * 2);
    short* QQh = (short*)alloc((size_t)4096 * 1024 * 2);
    short* QQl = (short*)alloc((size_t)4096 * 1024 * 2);
    short* KKh = (short*)alloc((size_t)4096 * 1024 * 2);
    short* KKl = (short*)alloc((size_t)4096 * 1024 * 2);
    short* VVp = (short*)alloc((size_t)4094 * 1024 * 2);
    float* CTX = (float*)alloc((size_t)4094 * 1024 * 4);

    dim3 tgrid(32, 32);
    transpose_split_kernel<<<tgrid, 256, 0, stream>>>(Wq, Wqt_h, Wqt_l);
    transpose_split_kernel<<<tgrid, 256, 0, stream>>>(Wk, Wkt_h, Wkt_l);
    transpose_split_kernel<<<tgrid, 256, 0, stream>>>(Wv, Wvt_h, nullptr);
    transpose_split_kernel<<<tgrid, 256, 0, stream>>>(Wo, Wot_h, nullptr);

    dim3 ggrid(16, 64);  // (N/64, Mtiles)
    gemm_kernel<1, 2><<<ggrid, 256, 0, stream>>>(q, 4096, Wqt_h, Wqt_l, bq, nullptr, QQh, QQl);
    gemm_kernel<1, 2><<<ggrid, 256, 0, stream>>>(k, 4096, Wkt_h, Wkt_l, bk, nullptr, KKh, KKl);
    gemm_kernel<0, 1><<<ggrid, 256, 0, stream>>>(v, 4094, Wvt_h, nullptr, bv, nullptr, VVp, nullptr);

    attn_kernel<<<dim3(2 * 16 * 32), 256, 0, stream>>>(QQh, QQl, KKh, KKl, VVp, att, CTX);

    gemm_kernel<0, 0><<<ggrid, 256, 0, stream>>>(CTX, 4094, Wot_h, nullptr, bo, out, nullptr, nullptr);
}

// Round 2
// 995.304 us; speedup vs baseline: 1.0541x; 1.0541x over previous
//
#include <hip/hip_runtime.h>

// ---------------------------------------------------------------------------
// MultiHeadAttention: B=2, S=2048, D=1024, H=16, DEPTH=64
// out  = (2, 2047, 1024) fp32   att = (2, 16, 2047, 2047) fp32
// bf16x3 split MFMA for Q/K path; plain bf16 for V/O path.
// All heavy staging via __builtin_amdgcn_global_load_lds (16B), chunk-major
// LDS layout [k-chunk][row] => lane-linear DMA + conflict-free ds_read_b128.
// ---------------------------------------------------------------------------

typedef __attribute__((ext_vector_type(8))) short bf16x8;
typedef __attribute__((ext_vector_type(4))) float f32x4;

#define MFMA_BF16(A, B, C) __builtin_amdgcn_mfma_f32_16x16x32_bf16(A, B, C, 0, 0, 0)

__device__ __forceinline__ short f2bf(float x) {
    unsigned u = __float_as_uint(x);
    u = u + 0x7FFFu + ((u >> 16) & 1u);   // RNE
    return (short)(u >> 16);
}
__device__ __forceinline__ float bf2f(short s) {
    return __uint_as_float(((unsigned)(unsigned short)s) << 16);
}
__device__ __forceinline__ int imin(int a, int b) { return a < b ? a : b; }

// async global->LDS, 16B per lane; lds ptr per-lane = wave base + lane*16
__device__ __forceinline__ void dma16(const short* g, short* l) {
    __builtin_amdgcn_global_load_lds(
        (const __attribute__((address_space(1))) unsigned int*)g,
        (__attribute__((address_space(3))) unsigned int*)l, 16, 0, 0);
}

// ---------------------------------------------------------------------------
// Transpose 1024x1024 W -> T[n][k] = W[k][n], split into bf16 hi (+ opt lo)
// ---------------------------------------------------------------------------
__global__ __launch_bounds__(256) void transpose_split_kernel(
    const float* __restrict__ W, short* __restrict__ Thi, short* __restrict__ Tlo) {
    __shared__ float tile[32][33];
    const int tx = threadIdx.x & 31, ty = threadIdx.x >> 5;
    const int k0 = blockIdx.x * 32, n0 = blockIdx.y * 32;
#pragma unroll
    for (int p = 0; p < 4; ++p)
        tile[ty + p * 8][tx] = W[(size_t)(k0 + ty + p * 8) * 1024 + n0 + tx];
    __syncthreads();
#pragma unroll
    for (int p = 0; p < 4; ++p) {
        int n = n0 + ty + p * 8, k = k0 + tx;
        float x = tile[tx][ty + p * 8];
        short h = f2bf(x);
        Thi[(size_t)n * 1024 + k] = h;
        if (Tlo) Tlo[(size_t)n * 1024 + k] = f2bf(x - bf2f(h));
    }
}

// ---------------------------------------------------------------------------
// fp32 -> bf16 hi (+ optional lo) elementwise split, 8 elems/thread
// ---------------------------------------------------------------------------
__global__ __launch_bounds__(256) void split_kernel(
    const float* __restrict__ X, short* __restrict__ Hi, short* __restrict__ Lo, int n8) {
    int idx = blockIdx.x * 256 + threadIdx.x;
    if (idx >= n8) return;
    float4 x0 = *((const float4*)X + (size_t)idx * 2);
    float4 x1 = *((const float4*)X + (size_t)idx * 2 + 1);
    float xs[8] = {x0.x, x0.y, x0.z, x0.w, x1.x, x1.y, x1.z, x1.w};
    bf16x8 hv, lv;
#pragma unroll
    for (int e = 0; e < 8; ++e) {
        short h = f2bf(xs[e]);
        hv[e] = h;
        lv[e] = f2bf(xs[e] - bf2f(h));
    }
    *(bf16x8*)&Hi[(size_t)idx * 8] = hv;
    if (Lo) *(bf16x8*)&Lo[(size_t)idx * 8] = lv;
}

// ---------------------------------------------------------------------------
// GEMM: C[M x 1024] = A[M x 1024] @ Bt^T + bias  (Bt[n][k] pre-transposed)
// A, Bt in bf16 (hi and, if SPLIT, lo). Tile 128(M) x 64(N), BK=32.
// 256 threads / 4 waves, wave quadrant 64x32 = 4x2 frags of 16x16x32.
// LDS chunk-major: A [c=4][row=128], B [c=4][row=64]; DMA lane-linear.
// OUTMODE: 0 = fp32 Cf, 1 = bf16 Chi, 2 = bf16 hi/lo (scaled).
// ---------------------------------------------------------------------------
template <int SPLIT, int OUTMODE>
__global__ __launch_bounds__(256) void gemm_dma(
    const short* __restrict__ Ahg, const short* __restrict__ Alg, int M,
    const short* __restrict__ Bhg, const short* __restrict__ Blg,
    const float* __restrict__ bias, float scale,
    float* __restrict__ Cf, short* __restrict__ Chi, short* __restrict__ Clo) {
    __shared__ __align__(16) short Ah[512 * 8];
    __shared__ __align__(16) short Al[SPLIT ? 512 * 8 : 8];
    __shared__ __align__(16) short Bh[256 * 8];
    __shared__ __align__(16) short Bl[SPLIT ? 256 * 8 : 8];

    const int tid = threadIdx.x;
    const int w = tid >> 6, lane = tid & 63;
    const int quad = lane >> 4, l16 = lane & 15;
    const int m0 = blockIdx.y * 128, n0 = blockIdx.x * 64;
    const int row0 = (w & 1) * 64, col0 = (w >> 1) * 32;

    f32x4 acc[4][2];
#pragma unroll
    for (int mi = 0; mi < 4; ++mi)
#pragma unroll
        for (int ni = 0; ni < 2; ++ni) acc[mi][ni] = (f32x4){0.f, 0.f, 0.f, 0.f};

    const int a_row = tid & 127;
    const int a_gr = imin(m0 + a_row, M - 1);
    const int b_gr = n0 + (tid & 63);
    const int b_c = tid >> 6;

    for (int k0 = 0; k0 < 1024; k0 += 32) {
        __syncthreads();
#pragma unroll
        for (int p = 0; p < 2; ++p) {
            int c = (p * 256 + tid) >> 7;
            const size_t go = (size_t)a_gr * 1024 + k0 + c * 8;
            dma16(Ahg + go, &Ah[(p * 256 + tid) * 8]);
            if (SPLIT) dma16(Alg + go, &Al[(p * 256 + tid) * 8]);
        }
        {
            const size_t go = (size_t)b_gr * 1024 + k0 + b_c * 8;
            dma16(Bhg + go, &Bh[tid * 8]);
            if (SPLIT) dma16(Blg + go, &Bl[tid * 8]);
        }
        __syncthreads();

        bf16x8 af[4], afl[4], bfr[2], bfl[2];
#pragma unroll
        for (int mi = 0; mi < 4; ++mi) {
            int r = row0 + mi * 16 + l16;
            af[mi] = *(const bf16x8*)&Ah[(quad * 128 + r) * 8];
            if (SPLIT) afl[mi] = *(const bf16x8*)&Al[(quad * 128 + r) * 8];
        }
#pragma unroll
        for (int ni = 0; ni < 2; ++ni) {
            int cdx = col0 + ni * 16 + l16;
            bfr[ni] = *(const bf16x8*)&Bh[(quad * 64 + cdx) * 8];
            if (SPLIT) bfl[ni] = *(const bf16x8*)&Bl[(quad * 64 + cdx) * 8];
        }
#pragma unroll
        for (int mi = 0; mi < 4; ++mi)
#pragma unroll
            for (int ni = 0; ni < 2; ++ni) {
                acc[mi][ni] = MFMA_BF16(af[mi], bfr[ni], acc[mi][ni]);
                if (SPLIT) {
                    acc[mi][ni] = MFMA_BF16(af[mi], bfl[ni], acc[mi][ni]);
                    acc[mi][ni] = MFMA_BF16(afl[mi], bfr[ni], acc[mi][ni]);
                }
            }
    }

#pragma unroll
    for (int ni = 0; ni < 2; ++ni) {
        int col = n0 + col0 + ni * 16 + l16;
        float bv = bias[col];
#pragma unroll
        for (int mi = 0; mi < 4; ++mi) {
#pragma unroll
            for (int r = 0; r < 4; ++r) {
                int row = m0 + row0 + mi * 16 + quad * 4 + r;
                if (row < M) {
                    float c = (acc[mi][ni][r] + bv) * scale;
                    size_t off = (size_t)row * 1024 + col;
                    if (OUTMODE == 0) {
                        Cf[off] = c;
                    } else if (OUTMODE == 1) {
                        Chi[off] = f2bf(c);
                    } else {
                        short h = f2bf(c);
                        Chi[off] = h;
                        Clo[off] = f2bf(c - bf2f(h));
                    }
                }
            }
        }
    }
}

// ---------------------------------------------------------------------------
// VV [ (b*2047+seq)*1024 + h*64 + d ] -> VT [ ((b*16+h)*64+d)*2048 + seq ]
// (row pad to 2048; pad col written as 0)
// ---------------------------------------------------------------------------
__global__ __launch_bounds__(256) void transpose_v_kernel(
    const short* __restrict__ VV, short* __restrict__ VT) {
    __shared__ short t[64][72];
    const int tid = threadIdx.x;
    const int st = blockIdx.x & 31, bh = blockIdx.x >> 5;
    const int b = bh >> 4, h = bh & 15;
    const int s0 = st * 64;
    {
        int seq = s0 + (tid >> 2), d0 = (tid & 3) * 16;
        int seqc = imin(seq, 2046);
        const short* src = VV + ((size_t)(b * 2047 + seqc)) * 1024 + h * 64 + d0;
        bf16x8 v0 = *(const bf16x8*)src;
        bf16x8 v1 = *(const bf16x8*)(src + 8);
        bool ok = (seq <= 2046);
#pragma unroll
        for (int e = 0; e < 8; ++e) {
            t[d0 + e][tid >> 2] = ok ? v0[e] : (short)0;
            t[d0 + 8 + e][tid >> 2] = ok ? v1[e] : (short)0;
        }
    }
    __syncthreads();
    {
        int d = tid >> 2, sc2 = (tid & 3) * 16;
        bf16x8 o0, o1;
#pragma unroll
        for (int e = 0; e < 8; ++e) {
            o0[e] = t[d][sc2 + e];
            o1[e] = t[d][sc2 + 8 + e];
        }
        short* dst = VT + ((size_t)(bh * 64 + d)) * 2048 + s0 + sc2;
        *(bf16x8*)dst = o0;
        *(bf16x8*)(dst + 8) = o1;
    }
}

// ---------------------------------------------------------------------------
// Fused causal attention. QQ pre-scaled by 1/8 and split hi/lo; KK split.
// att[b,h,i,j] = softmax_{j<=i}( QQ[b,i+1,h]·KK[b,j,h] ), ctx -> CTX (bf16).
// Block = 64 q-rows (4 waves x 16). 64-key tiles, two passes.
// Pass A (denominators): K-hi only. Pass B: full split + att write + PV.
// LDS chunk-major [cc][row]; staged via dma16.
// ---------------------------------------------------------------------------
__global__ __launch_bounds__(256) void attn_kernel(
    const short* __restrict__ QQh, const short* __restrict__ QQl,
    const short* __restrict__ KKh, const short* __restrict__ KKl,
    const short* __restrict__ VT,
    float* __restrict__ att, short* __restrict__ CTX) {
    __shared__ __align__(16) short Kh[512 * 8];   // [cc=8][key=64]
    __shared__ __align__(16) short Kl[512 * 8];
    __shared__ __align__(16) short Vt[512 * 8];   // [kc=8][d=64]
    __shared__ __align__(16) short Ps[4][16 * 72];

    const int tid = threadIdx.x;
    const int w = tid >> 6, lane = tid & 63;
    const int quad = lane >> 4, l16 = lane & 15;
    const int bx = blockIdx.x;
    const int qt = 31 - (bx >> 5);          // global work-descending order
    const int bh = bx & 31;
    const int h = bh & 15, b = bh >> 4;
    const int i0 = qt * 64;

    const int i_frag = i0 + w * 16 + l16;
    const int qrow = imin(i_frag + 1, 2047);
    const size_t qoff = ((size_t)(b * 2048 + qrow)) * 1024 + h * 64;
    const bf16x8 qh0 = *(const bf16x8*)&QQh[qoff + 0 + quad * 8];
    const bf16x8 qh1 = *(const bf16x8*)&QQh[qoff + 32 + quad * 8];
    const bf16x8 ql0 = *(const bf16x8*)&QQl[qoff + 0 + quad * 8];
    const bf16x8 ql1 = *(const bf16x8*)&QQl[qoff + 32 + quad * 8];

    const int i_max = imin(i0 + 63, 2046);
    const int jt_max = i_max >> 6;
    const int wave_imax = imin(i0 + w * 16 + 15, 2046);
    const int rowbase = i0 + w * 16 + quad * 4;

    const int dma_key = tid & 63;
    const int dma_cc0 = tid >> 6;

    float lsum[4] = {0.f, 0.f, 0.f, 0.f};

    // ---------------- PASS A: softmax denominators (K-hi only) --------------
    for (int jt = 0; jt <= jt_max; ++jt) {
        const int j0 = jt * 64;
        __syncthreads();
#pragma unroll
        for (int p = 0; p < 2; ++p) {
            int cc = p * 4 + dma_cc0;
            dma16(KKh + ((size_t)(b * 2048 + j0 + dma_key)) * 1024 + h * 64 + cc * 8,
                  &Kh[(p * 256 + tid) * 8]);
        }
        __syncthreads();
        if (j0 <= wave_imax) {
#pragma unroll
            for (int s = 0; s < 4; ++s) {
                f32x4 sc = (f32x4){0.f, 0.f, 0.f, 0.f};
#pragma unroll
                for (int c = 0; c < 2; ++c) {
                    bf16x8 kh = *(const bf16x8*)&Kh[((c * 4 + quad) * 64 + s * 16 + l16) * 8];
                    sc = MFMA_BF16(c ? qh1 : qh0, kh, sc);
                    sc = MFMA_BF16(c ? ql1 : ql0, kh, sc);
                }
                int j = j0 + s * 16 + l16;
#pragma unroll
                for (int r = 0; r < 4; ++r) {
                    int i = rowbase + r;
                    if (j <= i && i <= 2046) lsum[r] += __expf(sc[r]);
                }
            }
        }
    }
#pragma unroll
    for (int m = 1; m < 16; m <<= 1) {
#pragma unroll
        for (int r = 0; r < 4; ++r) lsum[r] += __shfl_xor(lsum[r], m, 64);
    }
    float linv[4];
#pragma unroll
    for (int r = 0; r < 4; ++r) linv[r] = 1.0f / lsum[r];

    f32x4 cacc[4];
#pragma unroll
    for (int t = 0; t < 4; ++t) cacc[t] = (f32x4){0.f, 0.f, 0.f, 0.f};

    // ---------------- PASS B: att writes + PV -------------------------------
    for (int jt = 0; jt <= jt_max; ++jt) {
        const int j0 = jt * 64;
        __syncthreads();
#pragma unroll
        for (int p = 0; p < 2; ++p) {
            int cc = p * 4 + dma_cc0;
            const size_t ko = ((size_t)(b * 2048 + j0 + dma_key)) * 1024 + h * 64 + cc * 8;
            dma16(KKh + ko, &Kh[(p * 256 + tid) * 8]);
            dma16(KKl + ko, &Kl[(p * 256 + tid) * 8]);
            dma16(VT + ((size_t)(bh * 64 + dma_key)) * 2048 + j0 + cc * 8,
                  &Vt[(p * 256 + tid) * 8]);
        }
        __syncthreads();
        if (j0 <= wave_imax) {
#pragma unroll
            for (int s = 0; s < 4; ++s) {
                f32x4 sc = (f32x4){0.f, 0.f, 0.f, 0.f};
#pragma unroll
                for (int c = 0; c < 2; ++c) {
                    const int ci = ((c * 4 + quad) * 64 + s * 16 + l16) * 8;
                    bf16x8 kh = *(const bf16x8*)&Kh[ci];
                    bf16x8 kl = *(const bf16x8*)&Kl[ci];
                    bf16x8 ah = c ? qh1 : qh0;
                    bf16x8 al = c ? ql1 : ql0;
                    sc = MFMA_BF16(ah, kh, sc);
                    sc = MFMA_BF16(ah, kl, sc);
                    sc = MFMA_BF16(al, kh, sc);
                }
                int j = j0 + s * 16 + l16;
#pragma unroll
                for (int r = 0; r < 4; ++r) {
                    int i = rowbase + r;
                    bool valid = (j <= i) && (i <= 2046);
                    float p = valid ? __expf(sc[r]) * linv[r] : 0.0f;
                    if (i <= 2046 && j <= 2046)
                        att[((size_t)bh * 2047 + i) * 2047 + j] = p;
                    Ps[w][(quad * 4 + r) * 72 + s * 16 + l16] = f2bf(p);
                }
            }
#pragma unroll
            for (int c = 0; c < 2; ++c) {
                bf16x8 pa = *(const bf16x8*)&Ps[w][l16 * 72 + c * 32 + quad * 8];
#pragma unroll
                for (int t = 0; t < 4; ++t) {
                    bf16x8 vb = *(const bf16x8*)&Vt[((c * 4 + quad) * 64 + t * 16 + l16) * 8];
                    cacc[t] = MFMA_BF16(pa, vb, cacc[t]);
                }
            }
        } else {
#pragma unroll
            for (int s = 0; s < 4; ++s) {
                int j = j0 + s * 16 + l16;
#pragma unroll
                for (int r = 0; r < 4; ++r) {
                    int i = rowbase + r;
                    if (i <= 2046 && j <= 2046)
                        att[((size_t)bh * 2047 + i) * 2047 + j] = 0.0f;
                }
            }
        }
    }

    // ctx -> CTX (bf16)
#pragma unroll
    for (int t = 0; t < 4; ++t) {
#pragma unroll
        for (int r = 0; r < 4; ++r) {
            int i = rowbase + r;
            if (i <= 2046)
                CTX[((size_t)(b * 2047 + i)) * 1024 + h * 64 + t * 16 + l16] = f2bf(cacc[t][r]);
        }
    }

    // zero tail: att cols beyond the block's causal tiles
    const int js = (jt_max + 1) * 64;
    for (int i = i0; i <= i_max; ++i) {
        float* rowp = att + ((size_t)bh * 2047 + i) * 2047;
        for (int cc2 = js + tid; cc2 < 2047; cc2 += 256) rowp[cc2] = 0.0f;
    }
}

// ---------------------------------------------------------------------------
extern "C" void kernel_launch(void* const* d_in, const int* in_sizes, int n_in,
                              void* d_out, int out_size, void* d_ws, size_t ws_size,
                              hipStream_t stream) {
    (void)in_sizes; (void)n_in; (void)out_size; (void)ws_size;
    const float* q  = (const float*)d_in[0];
    const float* k  = (const float*)d_in[1];
    const float* v  = (const float*)d_in[2];
    const float* Wq = (const float*)d_in[4];
    const float* bq = (const float*)d_in[5];
    const float* Wk = (const float*)d_in[6];
    const float* bk = (const float*)d_in[7];
    const float* Wv = (const float*)d_in[8];
    const float* bv = (const float*)d_in[9];
    const float* Wo = (const float*)d_in[10];
    const float* bo = (const float*)d_in[11];

    float* out = (float*)d_out;                     // 2*2047*1024
    float* att = out + (size_t)2 * 2047 * 1024;     // 2*16*2047*2047

    char* ws = (char*)d_ws;
    size_t off = 0;
    auto alloc = [&](size_t bytes) -> void* {
        void* p = ws + off;
        off += (bytes + 255) & ~(size_t)255;
        return p;
    };
    short* Wqt_h = (short*)alloc((size_t)1024 * 1024 * 2);
    short* Wqt_l = (short*)alloc((size_t)1024 * 1024 * 2);
    short* Wkt_h = (short*)alloc((size_t)1024 * 1024 * 2);
    short* Wkt_l = (short*)alloc((size_t)1024 * 1024 * 2);
    short* Wvt_h = (short*)alloc((size_t)1024 * 1024 * 2);
    short* Wot_h = (short*)alloc((size_t)1024 * 1024 * 2);
    short* Qhi = (short*)alloc((size_t)4096 * 1024 * 2);
    short* Qlo = (short*)alloc((size_t)4096 * 1024 * 2);
    short* Khi = (short*)alloc((size_t)4096 * 1024 * 2);
    short* Klo = (short*)alloc((size_t)4096 * 1024 * 2);
    short* Vbf = (short*)alloc((size_t)4096 * 1024 * 2);
    short* QQh = (short*)alloc((size_t)4096 * 1024 * 2);
    short* QQl = (short*)alloc((size_t)4096 * 1024 * 2);
    short* KKh = (short*)alloc((size_t)4096 * 1024 * 2);
    short* KKl = (short*)alloc((size_t)4096 * 1024 * 2);
    short* VV  = (short*)alloc((size_t)4096 * 1024 * 2);
    short* VT  = (short*)alloc((size_t)2048 * 2048 * 2 * 2);
    short* CTX = (short*)alloc((size_t)4096 * 1024 * 2);

    dim3 tgrid(32, 32);
    transpose_split_kernel<<<tgrid, 256, 0, stream>>>(Wq, Wqt_h, Wqt_l);
    transpose_split_kernel<<<tgrid, 256, 0, stream>>>(Wk, Wkt_h, Wkt_l);
    transpose_split_kernel<<<tgrid, 256, 0, stream>>>(Wv, Wvt_h, nullptr);
    transpose_split_kernel<<<tgrid, 256, 0, stream>>>(Wo, Wot_h, nullptr);

    split_kernel<<<2048, 256, 0, stream>>>(q, Qhi, Qlo, 4096 * 1024 / 8);
    split_kernel<<<2048, 256, 0, stream>>>(k, Khi, Klo, 4096 * 1024 / 8);
    split_kernel<<<2047, 256, 0, stream>>>(v, Vbf, nullptr, 4094 * 1024 / 8);

    dim3 ggrid(16, 32);  // (N/64, M/128)
    gemm_dma<1, 2><<<ggrid, 256, 0, stream>>>(Qhi, Qlo, 4096, Wqt_h, Wqt_l, bq, 0.125f,
                                              nullptr, QQh, QQl);
    gemm_dma<1, 2><<<ggrid, 256, 0, stream>>>(Khi, Klo, 4096, Wkt_h, Wkt_l, bk, 1.0f,
                                              nullptr, KKh, KKl);
    gemm_dma<0, 1><<<ggrid, 256, 0, stream>>>(Vbf, nullptr, 4094, Wvt_h, nullptr, bv, 1.0f,
                                              nullptr, VV, nullptr);

    transpose_v_kernel<<<dim3(32 * 32), 256, 0, stream>>>(VV, VT);

    attn_kernel<<<dim3(32 * 32), 256, 0, stream>>>(QQh, QQl, KKh, KKl, VT, att, CTX);

    gemm_dma<0, 0><<<ggrid, 256, 0, stream>>>(CTX, nullptr, 4094, Wot_h, nullptr, bo, 1.0f,
                                              out, nullptr, nullptr);
}